// Round 9
// baseline (17114.912 us; speedup 1.0000x reference)
//
#include <hip/hip_runtime.h>
#include <math.h>

// PointerNetDecoder on MI355X — round 9: round-8 design, compile fix only
// (nontemporal loads via clang native vector type instead of HIP_vector_type).
// j-split grid + surgical coherence: cross-block data (h,q,prev) via relaxed
// device-scope atomics (no acquire-invalidate -> L2 stays warm); weights
// L2-resident (same 128 KB slice per block every step); rW nontemporal;
// release-only tree barrier, capped spins; coop launch + plain fallback.

namespace {
constexpr int NB  = 512;
constexpr int S   = 128;
constexpr int H   = 512;
constexpr int NBLK = 512;

typedef float f32x4 __attribute__((ext_vector_type(4)));

__device__ __forceinline__ float ftanh(float x) {
  x = fminf(fmaxf(x, -15.f), 15.f);
  return 1.f - 2.f * __builtin_amdgcn_rcpf(__expf(2.f * x) + 1.f);
}
__device__ __forceinline__ float fsigm(float x) {
  x = fminf(fmaxf(x, -30.f), 30.f);
  return __builtin_amdgcn_rcpf(1.f + __expf(-x));
}
__device__ __forceinline__ float ld_dev(const float* p) {
  return __hip_atomic_load(const_cast<float*>(p), __ATOMIC_RELAXED,
                           __HIP_MEMORY_SCOPE_AGENT);
}
__device__ __forceinline__ void st_dev(float* p, float v) {
  __hip_atomic_store(p, v, __ATOMIC_RELAXED, __HIP_MEMORY_SCOPE_AGENT);
}

// 3-level tree barrier: release-adds (writeback only, no invalidate),
// relaxed polls, capped spins (broken barrier -> wrong results, not hang).
__device__ __forceinline__ void gridbar(int* bars, int bid, int& bseq) {
  __syncthreads();
  if (threadIdx.x == 0) {
    ++bseq;
    const int g = bid >> 6;
    int* arr  = &bars[g * 32];
    int* root = &bars[8 * 32];
    int* go   = &bars[(9 + g) * 32];
    __hip_atomic_fetch_add(arr, 1, __ATOMIC_RELEASE, __HIP_MEMORY_SCOPE_AGENT);
    if ((bid & 63) == 0) {
      int it = 0;
      while (__hip_atomic_load(arr, __ATOMIC_RELAXED, __HIP_MEMORY_SCOPE_AGENT)
                 < bseq * 64 && ++it < (1 << 16))
        __builtin_amdgcn_s_sleep(8);
      __hip_atomic_fetch_add(root, 1, __ATOMIC_RELEASE, __HIP_MEMORY_SCOPE_AGENT);
      it = 0;
      while (__hip_atomic_load(root, __ATOMIC_RELAXED, __HIP_MEMORY_SCOPE_AGENT)
                 < bseq * 8 && ++it < (1 << 16))
        __builtin_amdgcn_s_sleep(8);
      __hip_atomic_store(go, bseq, __ATOMIC_RELAXED, __HIP_MEMORY_SCOPE_AGENT);
    } else {
      int it = 0;
      while (__hip_atomic_load(go, __ATOMIC_RELAXED, __HIP_MEMORY_SCOPE_AGENT)
                 < bseq && ++it < (1 << 16))
        __builtin_amdgcn_s_sleep(8);
    }
  }
  __syncthreads();
  __builtin_amdgcn_sched_barrier(0);
}
} // namespace

// ---------------- zero barrier counters --------------------------------------
__global__ void k_zero(int* bars) {
  if (threadIdx.x < 17 * 32) bars[threadIdx.x] = 0;
}

// ---------------- rW = r @ w_ref : [65536,512] x [512,512] (once) ------------
__global__ __launch_bounds__(256) void k_rw(const float* __restrict__ r,
                                            const float* __restrict__ wref,
                                            float* __restrict__ rW) {
  __shared__ float As[16][64];
  __shared__ float Bs[16][64];
  const int tid = threadIdx.x;
  const int tx = tid & 15, ty = tid >> 4;
  const int M0 = blockIdx.x * 64, N0 = blockIdx.y * 64;
  float acc[4][4] = {};
  for (int k0 = 0; k0 < H; k0 += 16) {
    {
      int row = tid >> 2, c4 = (tid & 3) * 4;
      float4 a = *(const float4*)&r[(size_t)(M0 + row) * H + k0 + c4];
      As[c4+0][row] = a.x; As[c4+1][row] = a.y; As[c4+2][row] = a.z; As[c4+3][row] = a.w;
    }
    {
      int row = tid >> 4, c4 = (tid & 15) * 4;
      *(float4*)&Bs[row][c4] = *(const float4*)&wref[(size_t)(k0 + row) * H + N0 + c4];
    }
    __syncthreads();
#pragma unroll
    for (int kk = 0; kk < 16; ++kk) {
      float4 a = *(float4*)&As[kk][ty*4];
      float4 b = *(float4*)&Bs[kk][tx*4];
      float av[4] = {a.x,a.y,a.z,a.w}, bv[4] = {b.x,b.y,b.z,b.w};
#pragma unroll
      for (int i = 0; i < 4; ++i)
#pragma unroll
        for (int j = 0; j < 4; ++j) acc[i][j] += av[i]*bv[j];
    }
    __syncthreads();
  }
#pragma unroll
  for (int i = 0; i < 4; ++i)
    *(float4*)&rW[(size_t)(M0 + ty*4 + i) * H + N0 + tx*4] =
        make_float4(acc[i][0], acc[i][1], acc[i][2], acc[i][3]);
}

// ---------------- the decode loop ---------------------------------------------
struct LoopArgs {
  const float *x, *h0, *c0, *Wih, *Whh, *bih, *bhh, *wq, *v, *bos;
  float *hb0, *hb1, *c, *q, *prev, *rW, *out_tour, *out_ll;
  int *bars;
};

__global__ __launch_bounds__(256, 2) void k_loop(LoopArgs a) {
  const int tid = threadIdx.x;
  const int bid = blockIdx.x;
  const int lane = tid & 63, wave = tid >> 6;
  int bseq = 0;

  __shared__ float Hs[32][68];
  __shared__ float Ws[32][68];
  __shared__ float qs[H];
  __shared__ float sc_[S];
  __shared__ unsigned short alive_[S];
  __shared__ unsigned short inv_[S];
  __shared__ int   cnt_;
  __shared__ float ll_;

  // ---- init ----
  {
    for (int i = bid * 256 + tid; i < NB * H; i += NBLK * 256)
      st_dev(&a.hb0[i], a.h0[i]);
    if (bid < 256) {    // A-block owns c slice [64n x 16j]
      const int n0 = (bid >> 5) * 64, j0 = (bid & 31) * 16;
      for (int i = tid; i < 64 * 16; i += 256) {
        int nn = i >> 4, jj = i & 15;
        a.c[(size_t)(n0 + nn) * H + j0 + jj] = a.c0[(size_t)(n0 + nn) * H + j0 + jj];
      }
    }
    if (tid == 0) {
      st_dev(&a.prev[2 * bid], a.bos[0]);
      st_dev(&a.prev[2 * bid + 1], a.bos[1]);
    }
    for (int i = tid; i < S; i += 256) {
      alive_[i] = (unsigned short)i;
      inv_[i]   = (unsigned short)i;
    }
    if (tid == 0) { cnt_ = S; ll_ = 0.f; }
  }
  const float4 vA = *(const float4*)&a.v[lane * 8];
  const float4 vB = *(const float4*)&a.v[lane * 8 + 4];
  gridbar(a.bars, bid, bseq);

  const int tc = tid & 15, tn = tid >> 4;

  for (int t = 0; t < S; ++t) {
    const float* hin = (t & 1) ? a.hb1 : a.hb0;
    float* hout      = (t & 1) ? a.hb0 : a.hb1;

    // ---- phase A: gates tile (64n x 16j x 4g) + LSTM cell ----
    if (bid < 256) {
      const int n0 = (bid >> 5) * 64, j0 = (bid & 31) * 16;
      float acc[4][4] = {};
      for (int k0 = 0; k0 < H; k0 += 32) {
#pragma unroll
        for (int rep = 0; rep < 2; ++rep) {
          int u = tid + rep * 256;
          int row = u >> 3, cc = (u & 7) * 4;
          const float* hp = &hin[(size_t)(n0 + row) * H + k0 + cc];
          Hs[cc+0][row] = ld_dev(hp + 0);
          Hs[cc+1][row] = ld_dev(hp + 1);
          Hs[cc+2][row] = ld_dev(hp + 2);
          Hs[cc+3][row] = ld_dev(hp + 3);
          int jl = row & 15, g = row >> 4;
          float4 w4 = *(const float4*)&a.Whh[((size_t)g*H + j0 + jl)*H + k0 + cc];
          Ws[cc+0][jl*4+g] = w4.x; Ws[cc+1][jl*4+g] = w4.y;
          Ws[cc+2][jl*4+g] = w4.z; Ws[cc+3][jl*4+g] = w4.w;
        }
        __syncthreads();
#pragma unroll
        for (int kk = 0; kk < 32; ++kk) {
          float4 h4 = *(float4*)&Hs[kk][tn*4];
          float4 w4 = *(float4*)&Ws[kk][tc*4];
          acc[0][0] += h4.x*w4.x; acc[0][1] += h4.x*w4.y; acc[0][2] += h4.x*w4.z; acc[0][3] += h4.x*w4.w;
          acc[1][0] += h4.y*w4.x; acc[1][1] += h4.y*w4.y; acc[1][2] += h4.y*w4.z; acc[1][3] += h4.y*w4.w;
          acc[2][0] += h4.z*w4.x; acc[2][1] += h4.z*w4.y; acc[2][2] += h4.z*w4.z; acc[2][3] += h4.z*w4.w;
          acc[3][0] += h4.w*w4.x; acc[3][1] += h4.w*w4.y; acc[3][2] += h4.w*w4.z; acc[3][3] += h4.w*w4.w;
        }
        __syncthreads();
      }
      const int j = j0 + tc;
#pragma unroll
      for (int i = 0; i < 4; ++i) {
        int n = n0 + tn*4 + i;
        float p0 = ld_dev(&a.prev[2*n]), p1 = ld_dev(&a.prev[2*n+1]);
        float gv[4];
#pragma unroll
        for (int g = 0; g < 4; ++g) {
          int m = g*H + j;
          gv[g] = acc[i][g] + a.bih[m] + a.bhh[m] + p0*a.Wih[2*m] + p1*a.Wih[2*m+1];
        }
        float cv = a.c[(size_t)n*H + j];
        float cn = fsigm(gv[1])*cv + fsigm(gv[0])*ftanh(gv[2]);
        float hn = fsigm(gv[3])*ftanh(cn);
        a.c[(size_t)n*H + j] = cn;
        st_dev(&hout[(size_t)n*H + j], hn);
      }
    }
    gridbar(a.bars, bid, bseq);

    // ---- phase B: q tile (64n x 64c) ----
    if (bid < 64) {
      const int n0 = (bid >> 3) * 64, c0 = (bid & 7) * 64;
      float acc[4][4] = {};
      for (int k0 = 0; k0 < H; k0 += 32) {
#pragma unroll
        for (int rep = 0; rep < 2; ++rep) {
          int u = tid + rep * 256;
          int row = u >> 3, cc = (u & 7) * 4;
          const float* hp = &hout[(size_t)(n0 + row) * H + k0 + cc];
          Hs[cc+0][row] = ld_dev(hp + 0);
          Hs[cc+1][row] = ld_dev(hp + 1);
          Hs[cc+2][row] = ld_dev(hp + 2);
          Hs[cc+3][row] = ld_dev(hp + 3);
          int kr = u >> 4, cc2 = (u & 15) * 4;
          *(float4*)&Ws[kr][cc2] = *(const float4*)&a.wq[(size_t)(k0 + kr)*H + c0 + cc2];
        }
        __syncthreads();
#pragma unroll
        for (int kk = 0; kk < 32; ++kk) {
          float4 h4 = *(float4*)&Hs[kk][tn*4];
          float4 w4 = *(float4*)&Ws[kk][tc*4];
          acc[0][0] += h4.x*w4.x; acc[0][1] += h4.x*w4.y; acc[0][2] += h4.x*w4.z; acc[0][3] += h4.x*w4.w;
          acc[1][0] += h4.y*w4.x; acc[1][1] += h4.y*w4.y; acc[1][2] += h4.y*w4.z; acc[1][3] += h4.y*w4.w;
          acc[2][0] += h4.z*w4.x; acc[2][1] += h4.z*w4.y; acc[2][2] += h4.z*w4.z; acc[2][3] += h4.z*w4.w;
          acc[3][0] += h4.w*w4.x; acc[3][1] += h4.w*w4.y; acc[3][2] += h4.w*w4.z; acc[3][3] += h4.w*w4.w;
        }
        __syncthreads();
      }
#pragma unroll
      for (int i = 0; i < 4; ++i) {
        float* qp = &a.q[(size_t)(n0 + tn*4 + i)*H + c0 + tc*4];
        st_dev(qp + 0, acc[i][0]); st_dev(qp + 1, acc[i][1]);
        st_dev(qp + 2, acc[i][2]); st_dev(qp + 3, acc[i][3]);
      }
    }
    gridbar(a.bars, bid, bseq);

    // ---- phase C: alive-list scoring for n = bid ----
    {
      for (int i = tid; i < H; i += 256) qs[i] = ld_dev(&a.q[(size_t)bid*H + i]);
      __syncthreads();
      const float4 qA = *(const float4*)&qs[lane*8];
      const float4 qB = *(const float4*)&qs[lane*8 + 4];
      const int cnt = cnt_;
      const float* rwn = a.rW + (size_t)bid * S * H + lane * 8;
#pragma unroll 1
      for (int c0 = wave * 8; c0 < cnt; c0 += 32) {
        int rows[8];
        f32x4 A0[8], A1[8];
#pragma unroll
        for (int rr = 0; rr < 8; ++rr) {
          int idx = c0 + rr; if (idx > cnt - 1) idx = cnt - 1;
          rows[rr] = alive_[idx];
        }
#pragma unroll
        for (int rr = 0; rr < 8; ++rr) {
          const float* rp = rwn + (size_t)rows[rr] * H;
          A0[rr] = __builtin_nontemporal_load((const f32x4*)rp);
          A1[rr] = __builtin_nontemporal_load((const f32x4*)(rp + 4));
        }
#pragma unroll
        for (int rr = 0; rr < 8; ++rr) {
          float sr = ftanh(A0[rr].x + qA.x)*vA.x + ftanh(A0[rr].y + qA.y)*vA.y
                   + ftanh(A0[rr].z + qA.z)*vA.z + ftanh(A0[rr].w + qA.w)*vA.w
                   + ftanh(A1[rr].x + qB.x)*vB.x + ftanh(A1[rr].y + qB.y)*vB.y
                   + ftanh(A1[rr].z + qB.z)*vB.z + ftanh(A1[rr].w + qB.w)*vB.w;
#pragma unroll
          for (int off = 32; off > 0; off >>= 1) sr += __shfl_down(sr, off);
          if (lane == 0) sc_[rows[rr]] = sr;
        }
      }
      __syncthreads();
      if (wave == 0) {
        const int cnt2 = cnt_;
        float bv = -3.4e38f; int bi = 1 << 30;
        for (int i = lane; i < cnt2; i += 64) {
          int s = alive_[i];
          float vv = sc_[s];
          if (vv > bv || (vv == bv && s < bi)) { bv = vv; bi = s; }
        }
#pragma unroll
        for (int off = 32; off > 0; off >>= 1) {
          float ov = __shfl_down(bv, off);
          int   oi = __shfl_down(bi, off);
          if (ov > bv || (ov == bv && oi < bi)) { bv = ov; bi = oi; }
        }
        bv = __shfl(bv, 0); bi = __shfl(bi, 0);
        float e = 0.f;
        for (int i = lane; i < cnt2; i += 64) e += __expf(sc_[alive_[i]] - bv);
#pragma unroll
        for (int off = 32; off > 0; off >>= 1) e += __shfl_down(e, off);
        if (lane == 0) {
          float nll = ll_ - logf(e);   // logp at argmax = -log(sumexp)
          ll_ = nll;
          a.out_ll[bid] = nll;
          a.out_tour[(size_t)bid*S + t] = (float)bi;
          int p = inv_[bi];
          unsigned short last = alive_[cnt2 - 1];
          alive_[p] = last;
          inv_[last] = (unsigned short)p;
          cnt_ = cnt2 - 1;
          st_dev(&a.prev[2*bid],     a.x[((size_t)bid*S + bi)*2 + 0]);
          st_dev(&a.prev[2*bid + 1], a.x[((size_t)bid*S + bi)*2 + 1]);
        }
      }
    }
    gridbar(a.bars, bid, bseq);
  }
}

extern "C" void kernel_launch(void* const* d_in, const int* in_sizes, int n_in,
                              void* d_out, int out_size, void* d_ws, size_t ws_size,
                              hipStream_t stream) {
  const float* x    = (const float*)d_in[0];
  const float* r    = (const float*)d_in[1];
  const float* h0   = (const float*)d_in[2];
  const float* c0   = (const float*)d_in[3];
  const float* Wih  = (const float*)d_in[4];
  const float* Whh  = (const float*)d_in[5];
  const float* bih  = (const float*)d_in[6];
  const float* bhh  = (const float*)d_in[7];
  const float* wref = (const float*)d_in[8];
  const float* wq   = (const float*)d_in[9];
  const float* v    = (const float*)d_in[10];
  const float* bos  = (const float*)d_in[11];
  float* out = (float*)d_out;                 // [NB*S tour | NB ll], f32
  float* ws  = (float*)d_ws;

  size_t off = 0;
  float* rW   = ws + off; off += (size_t)NB * S * H;   // 134.2 MB
  float* hb0  = ws + off; off += (size_t)NB * H;
  float* hb1  = ws + off; off += (size_t)NB * H;
  float* cbuf = ws + off; off += (size_t)NB * H;
  float* qbuf = ws + off; off += (size_t)NB * H;
  float* prev = ws + off; off += (size_t)NB * 2;
  int*   bars = (int*)(ws + off); off += 17 * 32;

  k_zero<<<1, 17 * 32, 0, stream>>>(bars);
  k_rw<<<dim3(NB * S / 64, H / 64), 256, 0, stream>>>(r, wref, rW);

  LoopArgs la;
  la.x = x; la.h0 = h0; la.c0 = c0; la.Wih = Wih; la.Whh = Whh;
  la.bih = bih; la.bhh = bhh; la.wq = wq; la.v = v; la.bos = bos;
  la.hb0 = hb0; la.hb1 = hb1; la.c = cbuf; la.q = qbuf; la.prev = prev;
  la.rW = rW; la.out_tour = out; la.out_ll = out + (size_t)NB * S;
  la.bars = bars;

  void* kargs[] = { &la };
  hipError_t err = hipLaunchCooperativeKernel((void*)k_loop, dim3(NBLK), dim3(256),
                                              kargs, 0, stream);
  if (err != hipSuccess) {
    // co-residency fallback: plain launch of the same kernel (512 blocks x 256
    // thr at <=128 VGPR / 21 KB LDS fit 2/CU, so all blocks still co-schedule;
    // capped spins prevent hangs if they don't).
    k_loop<<<dim3(NBLK), dim3(256), 0, stream>>>(la);
  }
}

// Round 10
// 15779.353 us; speedup vs baseline: 1.0846x; 1.0846x over previous
//
#include <hip/hip_runtime.h>
#include <math.h>

// PointerNetDecoder on MI355X — round 10: round-7 block-autonomous structure,
// upgraded for latency hiding: 128 blocks x 1024 threads (4 waves/SIMD),
// batched weight prefetch (8 f32x4 in flight/thread), NT rW loads (protect
// L2-resident weights), alive-list phase C with 4 waves/seq.

namespace {
constexpr int NB  = 512;
constexpr int S   = 128;
constexpr int H   = 512;
constexpr int G   = 4;                 // sequences per block
constexpr int NBLK = NB / G;           // 128 blocks

typedef float f32x4 __attribute__((ext_vector_type(4)));

__device__ __forceinline__ float ftanh(float x) {
  x = fminf(fmaxf(x, -15.f), 15.f);
  return 1.f - 2.f * __builtin_amdgcn_rcpf(__expf(2.f * x) + 1.f);
}
__device__ __forceinline__ float fsigm(float x) {
  x = fminf(fmaxf(x, -30.f), 30.f);
  return __builtin_amdgcn_rcpf(1.f + __expf(-x));
}
__device__ __forceinline__ float dot4(f32x4 h, f32x4 w) {
  return h.x * w.x + h.y * w.y + h.z * w.z + h.w * w.w;
}

// Performance-only alignment barrier (relaxed, capped spin, no fences).
__device__ __forceinline__ void align_bar(int* bar, int target) {
  __syncthreads();
  if (threadIdx.x == 0) {
    __hip_atomic_fetch_add(bar, 1, __ATOMIC_RELAXED, __HIP_MEMORY_SCOPE_AGENT);
    int it = 0;
    while (__hip_atomic_load(bar, __ATOMIC_RELAXED, __HIP_MEMORY_SCOPE_AGENT) < target
           && ++it < (1 << 20))
      __builtin_amdgcn_s_sleep(2);
  }
  __syncthreads();
}
} // namespace

__global__ void k_zero(int* bar) { if (threadIdx.x == 0) *bar = 0; }

// ---------------- pack weights once: k-major, 4-k bundles --------------------
// whhp[(k>>2)*8192 + (g*512+j)*4 + (k&3)] = Whh[(g*512+j)*512 + k]
// wqp [(k>>2)*2048 + j*4 + (k&3)]         = wq [k*512 + j]
__global__ __launch_bounds__(256) void k_pack(const float* __restrict__ Whh,
                                              const float* __restrict__ wq,
                                              float* __restrict__ whhp,
                                              float* __restrict__ wqp) {
  int i = blockIdx.x * 256 + threadIdx.x;
  if (i < 2048 * 512) {
    int m = i >> 9, k = i & 511;
    whhp[(size_t)(k >> 2) * 8192 + m * 4 + (k & 3)] = Whh[i];
  }
  int j2 = i - 2048 * 512;
  if (j2 >= 0 && j2 < 512 * 512) {
    int k = j2 >> 9, j = j2 & 511;
    wqp[(size_t)(k >> 2) * 2048 + j * 4 + (k & 3)] = wq[j2];
  }
}

// ---------------- rW = r @ w_ref : [65536,512] x [512,512] (once) ------------
__global__ __launch_bounds__(256) void k_rw(const float* __restrict__ r,
                                            const float* __restrict__ wref,
                                            float* __restrict__ rW) {
  __shared__ float As[16][64];
  __shared__ float Bs[16][64];
  const int tid = threadIdx.x;
  const int tx = tid & 15, ty = tid >> 4;
  const int M0 = blockIdx.x * 64, N0 = blockIdx.y * 64;
  float acc[4][4] = {};
  for (int k0 = 0; k0 < H; k0 += 16) {
    {
      int row = tid >> 2, c4 = (tid & 3) * 4;
      float4 a = *(const float4*)&r[(size_t)(M0 + row) * H + k0 + c4];
      As[c4+0][row] = a.x; As[c4+1][row] = a.y; As[c4+2][row] = a.z; As[c4+3][row] = a.w;
    }
    {
      int row = tid >> 4, c4 = (tid & 15) * 4;
      *(float4*)&Bs[row][c4] = *(const float4*)&wref[(size_t)(k0 + row) * H + N0 + c4];
    }
    __syncthreads();
#pragma unroll
    for (int kk = 0; kk < 16; ++kk) {
      float4 a = *(float4*)&As[kk][ty*4];
      float4 b = *(float4*)&Bs[kk][tx*4];
      float av[4] = {a.x,a.y,a.z,a.w}, bv[4] = {b.x,b.y,b.z,b.w};
#pragma unroll
      for (int i = 0; i < 4; ++i)
#pragma unroll
        for (int j = 0; j < 4; ++j) acc[i][j] += av[i]*bv[j];
    }
    __syncthreads();
  }
#pragma unroll
  for (int i = 0; i < 4; ++i)
    *(float4*)&rW[(size_t)(M0 + ty*4 + i) * H + N0 + tx*4] =
        make_float4(acc[i][0], acc[i][1], acc[i][2], acc[i][3]);
}

// ---------------- the whole decode, block-autonomous --------------------------
struct DecArgs {
  const float *x, *h0, *c0, *Wih, *bih, *bhh, *v, *bos;
  const float *whhp, *wqp, *rW;
  float *out_tour, *out_ll;
  int *bar;
};

__global__ __launch_bounds__(1024, 4) void k_decode(DecArgs a) {
  const int tid  = threadIdx.x;             // 0..1023
  const int b    = blockIdx.x;              // 0..127
  const int n0   = b * G;
  const int lane = tid & 63, wave = tid >> 6;   // 16 waves
  const int j    = tid & 511, nh = tid >> 9;    // j-column, seq-half

  __shared__ float h_[2][G][H];       // 16 KB
  __shared__ float c_[G][H];          //  8 KB
  __shared__ float q_[G][H];          //  8 KB
  __shared__ float sc_[G][S];         //  2 KB
  __shared__ unsigned short alive_[G][S];  // 1 KB
  __shared__ unsigned short inv_[G][S];    // 1 KB
  __shared__ int   cnt_[G];
  __shared__ float prev_[G][2];
  __shared__ float ll_[G];

  // ---- init state ----
  for (int i = tid; i < G * H; i += 1024) {
    int n = i >> 9, k = i & 511;
    h_[0][n][k] = a.h0[(size_t)(n0 + n) * H + k];
    c_[n][k]    = a.c0[(size_t)(n0 + n) * H + k];
  }
  for (int i = tid; i < G * S; i += 1024) {
    alive_[i >> 7][i & 127] = (unsigned short)(i & 127);
    inv_[i >> 7][i & 127]   = (unsigned short)(i & 127);
  }
  if (tid < G) {
    cnt_[tid] = S;
    ll_[tid] = 0.f;
    prev_[tid][0] = a.bos[0];
    prev_[tid][1] = a.bos[1];
  }

  // per-thread epilogue constants for column j (all 4 gates)
  float bsum[4], wi0[4], wi1[4];
#pragma unroll
  for (int g = 0; g < 4; ++g) {
    int m = g * H + j;
    bsum[g] = a.bih[m] + a.bhh[m];
    wi0[g]  = a.Wih[2 * m];
    wi1[g]  = a.Wih[2 * m + 1];
  }
  const f32x4 vA = *(const f32x4*)&a.v[lane * 8];
  const f32x4 vB = *(const f32x4*)&a.v[lane * 8 + 4];
  __syncthreads();

  for (int t = 0; t < S; ++t) {
    align_bar(a.bar, (t + 1) * NBLK);
    const int cur = t & 1, nxt = cur ^ 1;

    // ---- phase A: gates = h @ Whh^T (+ prev@Wih^T + b) -> LSTM cell ----
    // thread: column j, seqs {2nh, 2nh+1}, all 4 gates. unroll-2 batched loads.
    {
      float acc[2][4] = {};
      const float* hp0 = &h_[cur][nh * 2 + 0][0];
      const float* hp1 = &h_[cur][nh * 2 + 1][0];
#pragma unroll 1
      for (int k8 = 0; k8 < 64; ++k8) {
        const float* wpa = a.whhp + (size_t)k8 * 16384 + j * 4;
        f32x4 wa0 = *(const f32x4*)(wpa + 0);
        f32x4 wa1 = *(const f32x4*)(wpa + 2048);
        f32x4 wa2 = *(const f32x4*)(wpa + 4096);
        f32x4 wa3 = *(const f32x4*)(wpa + 6144);
        f32x4 wb0 = *(const f32x4*)(wpa + 8192);
        f32x4 wb1 = *(const f32x4*)(wpa + 10240);
        f32x4 wb2 = *(const f32x4*)(wpa + 12288);
        f32x4 wb3 = *(const f32x4*)(wpa + 14336);
        f32x4 h0a = *(const f32x4*)&hp0[k8 * 8];
        f32x4 h0b = *(const f32x4*)&hp0[k8 * 8 + 4];
        f32x4 h1a = *(const f32x4*)&hp1[k8 * 8];
        f32x4 h1b = *(const f32x4*)&hp1[k8 * 8 + 4];
        acc[0][0] += dot4(h0a, wa0) + dot4(h0b, wb0);
        acc[0][1] += dot4(h0a, wa1) + dot4(h0b, wb1);
        acc[0][2] += dot4(h0a, wa2) + dot4(h0b, wb2);
        acc[0][3] += dot4(h0a, wa3) + dot4(h0b, wb3);
        acc[1][0] += dot4(h1a, wa0) + dot4(h1b, wb0);
        acc[1][1] += dot4(h1a, wa1) + dot4(h1b, wb1);
        acc[1][2] += dot4(h1a, wa2) + dot4(h1b, wb2);
        acc[1][3] += dot4(h1a, wa3) + dot4(h1b, wb3);
      }
#pragma unroll
      for (int i = 0; i < 2; ++i) {
        int n = nh * 2 + i;
        float p0 = prev_[n][0], p1 = prev_[n][1];
        float gv[4];
#pragma unroll
        for (int g = 0; g < 4; ++g)
          gv[g] = acc[i][g] + bsum[g] + p0 * wi0[g] + p1 * wi1[g];
        float cv = c_[n][j];
        float cn = fsigm(gv[1]) * cv + fsigm(gv[0]) * ftanh(gv[2]);
        float hn = fsigm(gv[3]) * ftanh(cn);
        c_[n][j] = cn;
        h_[nxt][n][j] = hn;
      }
    }
    __syncthreads();

    // ---- phase B: q = h_new @ wq ----
    {
      float accq[2] = {};
      const float* hp0 = &h_[nxt][nh * 2 + 0][0];
      const float* hp1 = &h_[nxt][nh * 2 + 1][0];
#pragma unroll 1
      for (int k8 = 0; k8 < 64; ++k8) {
        const float* wp = a.wqp + (size_t)k8 * 4096 + j * 4;
        f32x4 w0 = *(const f32x4*)(wp + 0);
        f32x4 w1 = *(const f32x4*)(wp + 2048);
        f32x4 h0a = *(const f32x4*)&hp0[k8 * 8];
        f32x4 h0b = *(const f32x4*)&hp0[k8 * 8 + 4];
        f32x4 h1a = *(const f32x4*)&hp1[k8 * 8];
        f32x4 h1b = *(const f32x4*)&hp1[k8 * 8 + 4];
        accq[0] += dot4(h0a, w0) + dot4(h0b, w1);
        accq[1] += dot4(h1a, w0) + dot4(h1b, w1);
      }
      q_[nh * 2 + 0][j] = accq[0];
      q_[nh * 2 + 1][j] = accq[1];
    }
    __syncthreads();

    // ---- phase C: alive-list scoring; 4 waves per sequence ----
    {
      const int n  = wave >> 2;       // 0..3
      const int qr = wave & 3;
      const int cnt = cnt_[n];
      const f32x4 qA = *(const f32x4*)&q_[n][lane * 8];
      const f32x4 qB = *(const f32x4*)&q_[n][lane * 8 + 4];
      const float* rwn = a.rW + (size_t)(n0 + n) * S * H + lane * 8;
#pragma unroll 1
      for (int c0 = qr * 8; c0 < cnt; c0 += 32) {
        int rows[8];
        f32x4 A0[8], A1[8];
#pragma unroll
        for (int rr = 0; rr < 8; ++rr) {
          int idx = c0 + rr; if (idx > cnt - 1) idx = cnt - 1;  // tail dup ok
          rows[rr] = alive_[n][idx];
        }
#pragma unroll
        for (int rr = 0; rr < 8; ++rr) {
          const float* rp = rwn + (size_t)rows[rr] * H;
          A0[rr] = __builtin_nontemporal_load((const f32x4*)rp);
          A1[rr] = __builtin_nontemporal_load((const f32x4*)(rp + 4));
        }
#pragma unroll
        for (int rr = 0; rr < 8; ++rr) {
          float sr = ftanh(A0[rr].x + qA.x)*vA.x + ftanh(A0[rr].y + qA.y)*vA.y
                   + ftanh(A0[rr].z + qA.z)*vA.z + ftanh(A0[rr].w + qA.w)*vA.w
                   + ftanh(A1[rr].x + qB.x)*vB.x + ftanh(A1[rr].y + qB.y)*vB.y
                   + ftanh(A1[rr].z + qB.z)*vB.z + ftanh(A1[rr].w + qB.w)*vB.w;
#pragma unroll
          for (int off = 32; off > 0; off >>= 1) sr += __shfl_down(sr, off);
          if (lane == 0) sc_[n][rows[rr]] = sr;
        }
      }
    }
    __syncthreads();

    // ---- argmax + ll + state update over alive entries ----
    if (wave < G) {
      const int n = wave;
      const int cnt = cnt_[n];
      float bv = -3.4e38f; int bi = 1 << 30;
      for (int i = lane; i < cnt; i += 64) {
        int s = alive_[n][i];
        float vv = sc_[n][s];
        if (vv > bv || (vv == bv && s < bi)) { bv = vv; bi = s; }
      }
#pragma unroll
      for (int off = 32; off > 0; off >>= 1) {
        float ov = __shfl_down(bv, off);
        int   oi = __shfl_down(bi, off);
        if (ov > bv || (ov == bv && oi < bi)) { bv = ov; bi = oi; }
      }
      bv = __shfl(bv, 0); bi = __shfl(bi, 0);
      float e = 0.f;
      for (int i = lane; i < cnt; i += 64) e += __expf(sc_[n][alive_[n][i]] - bv);
#pragma unroll
      for (int off = 32; off > 0; off >>= 1) e += __shfl_down(e, off);
      if (lane == 0) {
        float nll = ll_[n] - logf(e);   // logp at argmax = -log(sumexp)
        ll_[n] = nll;
        a.out_ll[n0 + n] = nll;
        a.out_tour[(size_t)(n0 + n) * S + t] = (float)bi;
        int p = inv_[n][bi];
        unsigned short last = alive_[n][cnt - 1];
        alive_[n][p] = last;
        inv_[n][last] = (unsigned short)p;
        cnt_[n] = cnt - 1;
        prev_[n][0] = a.x[((size_t)(n0 + n) * S + bi) * 2 + 0];
        prev_[n][1] = a.x[((size_t)(n0 + n) * S + bi) * 2 + 1];
      }
    }
    __syncthreads();
  }
}

extern "C" void kernel_launch(void* const* d_in, const int* in_sizes, int n_in,
                              void* d_out, int out_size, void* d_ws, size_t ws_size,
                              hipStream_t stream) {
  const float* x    = (const float*)d_in[0];
  const float* r    = (const float*)d_in[1];
  const float* h0   = (const float*)d_in[2];
  const float* c0   = (const float*)d_in[3];
  const float* Wih  = (const float*)d_in[4];
  const float* Whh  = (const float*)d_in[5];
  const float* bih  = (const float*)d_in[6];
  const float* bhh  = (const float*)d_in[7];
  const float* wref = (const float*)d_in[8];
  const float* wq   = (const float*)d_in[9];
  const float* v    = (const float*)d_in[10];
  const float* bos  = (const float*)d_in[11];
  float* out = (float*)d_out;                 // [NB*S tour | NB ll], f32
  float* ws  = (float*)d_ws;

  size_t off = 0;
  float* rW   = ws + off; off += (size_t)NB * S * H;   // 134.2 MB
  float* whhp = ws + off; off += (size_t)4 * H * H;    // 4 MB
  float* wqp  = ws + off; off += (size_t)H * H;        // 1 MB
  int*   bar  = (int*)(ws + off); off += 16;

  k_zero<<<1, 64, 0, stream>>>(bar);
  k_pack<<<(2048*512 + 512*512 + 255) / 256, 256, 0, stream>>>(Whh, wq, whhp, wqp);
  k_rw<<<dim3(NB * S / 64, H / 64), 256, 0, stream>>>(r, wref, rW);

  DecArgs da;
  da.x = x; da.h0 = h0; da.c0 = c0; da.Wih = Wih; da.bih = bih; da.bhh = bhh;
  da.v = v; da.bos = bos; da.whhp = whhp; da.wqp = wqp; da.rW = rW;
  da.out_tour = out; da.out_ll = out + (size_t)NB * S;
  da.bar = bar;

  k_decode<<<NBLK, 1024, 0, stream>>>(da);
}